// Round 6
// baseline (619.889 us; speedup 1.0000x reference)
//
#include <hip/hip_runtime.h>

// AngularTensorProduct: out[e,r,l3,c] = sum_k pf[k] * a1[e,r,l1[k],c] * a2[e,r,l2[k],c]
// MAX_L=3 -> A=20 monomials, K=84 combos. [E,R,A,C] f32, E=100000 R=8 C=16.
// Memory-bound: compulsory 3.07 GB; float4-copy ceiling 6.29 TB/s -> 488 us floor.
// Ladder: R1 float2-gather 609 -> R3 float4+NT 601 (NT inflates WRITE, reverted)
// -> R4 LDS-staged dense load+store 578 -> R5 (drop output restage, direct
// cached scalar stores; L2 merges to exact compulsory) 541 us = 5.67 TB/s (90%
// of copy ceiling). R6: 100K tiny blocks -> 1792 persistent grid-stride blocks
// (7/CU, LDS-exact) + register prefetch of next tile's loads overlapping the
// current tile's compute+store (T14 reg-staged pipeline; padded LDS writes
// preclude global_load_lds). Targets block-dispatch rate + per-block VMEM drain.

#define NA 20
#define NK 84
#define TR 8      // rows (e,r) per tile
#define ROWQ 80   // float4 per row (A*C = 320 f32)
#define PADQ 82   // padded row stride in float4 (328 f32; 328%32==8 -> 2-way banks, free per m136)
#define NTH 128   // threads per block = TR*16 channel tasks
#define NBLK 1792 // 7 blocks/CU * 256 CU (LDS: 160K / 20.5K = 7)

typedef float f32x4 __attribute__((ext_vector_type(4)));

namespace atp {

// index of monomial (x,y,z) in the nested-loop l_list order
constexpr int lidx(int x, int y, int z) {
  int i = 0;
  for (int a = 0; a < x; ++a) i += (4 - a) * (5 - a) / 2;
  for (int b = 0; b < y; ++b) i += 4 - x - b;
  return i + z;
}

constexpr int combi(int n, int k) {
  int r = 1;
  for (int i = 1; i <= k; ++i) r = r * (n - k + i) / i;
  return r;
}

struct Tab {
  int l1[NK];
  int l2[NK];
  float pf[NK];
  int cnt[NA];
  int off[NA];
};

constexpr Tab make_tab() {
  Tab t{};
  int n = 0, m = 0;
  for (int x = 0; x <= 3; ++x)
    for (int y = 0; y <= 3 - x; ++y)
      for (int z = 0; z <= 3 - x - y; ++z) {
        t.off[m] = n;
        t.cnt[m] = (x + 1) * (y + 1) * (z + 1);
        for (int a = 0; a <= x; ++a)
          for (int b = 0; b <= y; ++b)
            for (int c = 0; c <= z; ++c) {
              t.l1[n] = lidx(a, b, c);
              t.l2[n] = lidx(x - a, y - b, z - c);
              t.pf[n] = (float)(combi(x, a) * combi(y, b) * combi(z, c));
              ++n;
            }
        ++m;
      }
  return t;
}

constexpr Tab T = make_tab();

}  // namespace atp

// Persistent block, grid-stride over 8-row tiles.
// Steady state per tile: {reg->LDS write; barrier; issue next tile's 10
// global_load_dwordx4 into regs; gather 40 scalars from padded LDS; 84 FMA;
// 20 direct cached scalar stores (L2-merged); barrier}. The prefetch loads'
// vmcnt is only waited at the NEXT iteration's ds_write -> they stay in
// flight under the whole compute+store phase.
__global__ __launch_bounds__(NTH) void atp_kernel(
    const float* __restrict__ in1, const float* __restrict__ in2,
    float* __restrict__ out, int n_tiles) {
  __shared__ f32x4 lds1[TR * PADQ];
  __shared__ f32x4 lds2[TR * PADQ];

  const int t = threadIdx.x;
  const int stride = gridDim.x;

  // per-thread staging slots (compile-time k -> static indices, rule #20)
  int srow[5], sqq[5];
#pragma unroll
  for (int k = 0; k < 5; ++k) {
    const int q = k * NTH + t;      // 0..639
    srow[k] = q / ROWQ;
    sqq[k] = q - srow[k] * ROWQ;
  }
  const int row = t >> 4;
  const int c = t & 15;
  const float* l1p = reinterpret_cast<const float*>(lds1) + row * (PADQ * 4) + c;
  const float* l2p = reinterpret_cast<const float*>(lds2) + row * (PADQ * 4) + c;

  long tile = blockIdx.x;
  const f32x4* g1 = reinterpret_cast<const f32x4*>(in1) + tile * (TR * ROWQ);
  const f32x4* g2 = reinterpret_cast<const f32x4*>(in2) + tile * (TR * ROWQ);

  // prologue: load first tile into regs
  f32x4 r1[5], r2[5];
#pragma unroll
  for (int k = 0; k < 5; ++k) {
    const int q = k * NTH + t;
    r1[k] = g1[q];
    r2[k] = g2[q];
  }

  while (tile < n_tiles) {
    // ---- staged regs -> padded LDS ----
#pragma unroll
    for (int k = 0; k < 5; ++k) {
      lds1[srow[k] * PADQ + sqq[k]] = r1[k];
      lds2[srow[k] * PADQ + sqq[k]] = r2[k];
    }
    __syncthreads();

    // ---- issue next tile's loads (in flight across compute+store) ----
    const long next = tile + stride;
    if (next < n_tiles) {
      const f32x4* n1 = g1 + (long)stride * (TR * ROWQ);
      const f32x4* n2 = g2 + (long)stride * (TR * ROWQ);
#pragma unroll
      for (int k = 0; k < 5; ++k) {
        const int q = k * NTH + t;
        r1[k] = n1[q];
        r2[k] = n2[q];
      }
      g1 = n1;
      g2 = n2;
    }

    // ---- gather + compute + direct stores for current tile ----
    float v1[NA], v2[NA];
#pragma unroll
    for (int a = 0; a < NA; ++a) v1[a] = l1p[a * 16];
#pragma unroll
    for (int a = 0; a < NA; ++a) v2[a] = l2p[a * 16];

    float* op = out + tile * (TR * ROWQ * 4) + row * (ROWQ * 4) + c;
#pragma unroll
    for (int i3 = 0; i3 < NA; ++i3) {
      float acc = 0.f;
#pragma unroll
      for (int j = 0; j < atp::T.cnt[i3]; ++j) {
        const int k = atp::T.off[i3] + j;             // compile-time
        acc = fmaf(atp::T.pf[k] * v1[atp::T.l1[k]], v2[atp::T.l2[k]], acc);
      }
      op[i3 * 16] = acc;   // cached scalar store; L2 merges to full lines
    }
    __syncthreads();       // LDS reads done before next iteration's writes
    tile = next;
  }
}

extern "C" void kernel_launch(void* const* d_in, const int* in_sizes, int n_in,
                              void* d_out, int out_size, void* d_ws, size_t ws_size,
                              hipStream_t stream) {
  const float* in1 = (const float*)d_in[0];
  const float* in2 = (const float*)d_in[1];
  float* out = (float*)d_out;
  const int n_tiles = out_size / (TR * NA * 16);  // = 100000
  const int blocks = n_tiles < NBLK ? n_tiles : NBLK;
  atp_kernel<<<blocks, NTH, 0, stream>>>(in1, in2, out, n_tiles);
}

// Round 7
// 552.336 us; speedup vs baseline: 1.1223x; 1.1223x over previous
//
#include <hip/hip_runtime.h>

// AngularTensorProduct: out[e,r,l3,c] = sum_k pf[k] * a1[e,r,l1[k],c] * a2[e,r,l2[k],c]
// MAX_L=3 -> A=20 monomials, K=84 combos. [E,R,A,C] f32, E=100000 R=8 C=16.
// Memory-bound: compulsory 3.07 GB; float4-copy ceiling 6.29 TB/s -> 488 us floor.
// Ladder: R1 float2-gather 609 | R3 float4+NT-stores 601 (NT stores inflate
// WRITE +12.5%: partial-line eviction -> never NT-store scattered outputs)
// | R4 LDS-staged dense load+store 578 | R5 drop output restage, direct cached
// scalar stores (L2 merges to exact compulsory) 541 = 5.67 TB/s (90% of copy
// ceiling) | R6 persistent+reg-prefetch 620 REGRESSION (VGPR=52 proves the
// compiler serialized the prefetch; short-block churn is better MLP than a
// register pipeline -> T14-null confirmed for this regime).
// R7: R5 + nontemporal LOADS (inputs are stream-once; full lines consumed per
// instruction so no merge hazard, frees L2 for output write-combining).

#define NA 20
#define NK 84
#define TR 8      // rows (e,r) per tile
#define ROWQ 80   // float4 per row (A*C = 320 f32)
#define PADQ 82   // padded row stride in float4 (328 f32; 328%32==8 -> 2-way banks, free per m136)
#define NTH 128   // threads per block = TR*16 channel tasks

typedef float f32x4 __attribute__((ext_vector_type(4)));

namespace atp {

// index of monomial (x,y,z) in the nested-loop l_list order
constexpr int lidx(int x, int y, int z) {
  int i = 0;
  for (int a = 0; a < x; ++a) i += (4 - a) * (5 - a) / 2;
  for (int b = 0; b < y; ++b) i += 4 - x - b;
  return i + z;
}

constexpr int combi(int n, int k) {
  int r = 1;
  for (int i = 1; i <= k; ++i) r = r * (n - k + i) / i;
  return r;
}

struct Tab {
  int l1[NK];
  int l2[NK];
  float pf[NK];
  int cnt[NA];
  int off[NA];
};

constexpr Tab make_tab() {
  Tab t{};
  int n = 0, m = 0;
  for (int x = 0; x <= 3; ++x)
    for (int y = 0; y <= 3 - x; ++y)
      for (int z = 0; z <= 3 - x - y; ++z) {
        t.off[m] = n;
        t.cnt[m] = (x + 1) * (y + 1) * (z + 1);
        for (int a = 0; a <= x; ++a)
          for (int b = 0; b <= y; ++b)
            for (int c = 0; c <= z; ++c) {
              t.l1[n] = lidx(a, b, c);
              t.l2[n] = lidx(x - a, y - b, z - c);
              t.pf[n] = (float)(combi(x, a) * combi(y, b) * combi(z, c));
              ++n;
            }
        ++m;
      }
  return t;
}

constexpr Tab T = make_tab();

}  // namespace atp

// Block = 128 threads = one 8-row tile (8*1280 B per tensor).
// Phase 1: stage both input tiles linearly into padded LDS (dense 1 KiB/wave
//          global segments — the m13 copy pattern), nontemporal hint.
// Phase 2: thread (row, c) gathers 20+20 scalars from LDS (2-way banks = free),
//          computes each of the 20 l3 outputs with compile-time register
//          indices (rule #20) and stores it DIRECTLY to global, interleaved
//          with the FMA chain. Scattered 4B cached stores merge to full lines
//          in L2 (R1/R5: WRITE_SIZE exactly compulsory).
__global__ __launch_bounds__(NTH) void atp_kernel(
    const float* __restrict__ in1, const float* __restrict__ in2,
    float* __restrict__ out) {
  __shared__ f32x4 lds1[TR * PADQ];
  __shared__ f32x4 lds2[TR * PADQ];

  const int t = threadIdx.x;
  const long base_q = (long)blockIdx.x * (TR * ROWQ);  // float4 index
  const f32x4* g1 = reinterpret_cast<const f32x4*>(in1) + base_q;
  const f32x4* g2 = reinterpret_cast<const f32x4*>(in2) + base_q;

  // ---- phase 1: linear global -> padded LDS (nontemporal reads) ----
#pragma unroll
  for (int k = 0; k < 5; ++k) {
    const int q = k * NTH + t;      // 0..639
    const int row = q / ROWQ;
    const int qq = q - row * ROWQ;
    lds1[row * PADQ + qq] = __builtin_nontemporal_load(g1 + q);
    lds2[row * PADQ + qq] = __builtin_nontemporal_load(g2 + q);
  }
  __syncthreads();

  // ---- phase 2: per-(row,c) compute from LDS, direct global stores ----
  const int row = t >> 4;
  const int c = t & 15;
  const float* l1p = reinterpret_cast<const float*>(lds1) + row * (PADQ * 4) + c;
  const float* l2p = reinterpret_cast<const float*>(lds2) + row * (PADQ * 4) + c;
  float* op = out + base_q * 4 + row * (ROWQ * 4) + c;

  float v1[NA], v2[NA];
#pragma unroll
  for (int a = 0; a < NA; ++a) v1[a] = l1p[a * 16];
#pragma unroll
  for (int a = 0; a < NA; ++a) v2[a] = l2p[a * 16];

#pragma unroll
  for (int i3 = 0; i3 < NA; ++i3) {
    float acc = 0.f;
#pragma unroll
    for (int j = 0; j < atp::T.cnt[i3]; ++j) {
      const int k = atp::T.off[i3] + j;               // compile-time
      acc = fmaf(atp::T.pf[k] * v1[atp::T.l1[k]], v2[atp::T.l2[k]], acc);
    }
    op[i3 * 16] = acc;   // cached scalar store; L2 merges to full lines
  }
}

extern "C" void kernel_launch(void* const* d_in, const int* in_sizes, int n_in,
                              void* d_out, int out_size, void* d_ws, size_t ws_size,
                              hipStream_t stream) {
  const float* in1 = (const float*)d_in[0];
  const float* in2 = (const float*)d_in[1];
  float* out = (float*)d_out;
  // out_size = E*R*A*C f32; tiles of TR rows of A*C floats each
  const int n_tiles = out_size / (TR * NA * 16);  // = 100000
  atp_kernel<<<n_tiles, NTH, 0, stream>>>(in1, in2, out);
}